// Round 1
// 201.681 us; speedup vs baseline: 1.0709x; 1.0709x over previous
//
#include <hip/hip_runtime.h>
#include <hip/hip_bf16.h>

typedef __hip_bfloat16 bf16;
typedef __attribute__((ext_vector_type(8))) short bf16x8;
typedef __attribute__((ext_vector_type(4))) float f32x4;

#define NNODE 512   // B*N

__device__ __forceinline__ float b2f(bf16 v){ return __bfloat162float(v); }
__device__ __forceinline__ float siluf(float x){ return x / (1.f + __expf(-x)); }
__device__ __forceinline__ float tanhfast(float x){ return 1.f - 2.f/(__expf(2.f*x)+1.f); }
__device__ __forceinline__ float celu2(float x){ return x > 0.f ? x : 2.f*(__expf(0.5f*x)-1.f); }
__device__ __forceinline__ float bs2f(short v){ union{unsigned int i; float f;} t; t.i = ((unsigned int)(unsigned short)v) << 16; return t.f; }
__device__ __forceinline__ short f2bs(float x){ union{ bf16 b; short s; } u; u.b = __float2bfloat16(x); return u.s; }
__device__ __forceinline__ float lo16f(unsigned int u){ union{unsigned int i; float f;} t; t.i = u<<16; return t.f; }
__device__ __forceinline__ float hi16f(unsigned int u){ union{unsigned int i; float f;} t; t.i = u & 0xffff0000u; return t.f; }

// ---- dtype-polymorphic scalar load/store -------------------------------------------
template<typename T> __device__ __forceinline__ float ldv(const void* p, int i);
template<> __device__ __forceinline__ float ldv<float>(const void* p, int i){ return ((const float*)p)[i]; }
template<> __device__ __forceinline__ float ldv<bf16 >(const void* p, int i){ return b2f(((const bf16*)p)[i]); }

template<typename T> __device__ __forceinline__ void stv(void* p, int i, float v);
template<> __device__ __forceinline__ void stv<float>(void* p, int i, float v){ ((float*)p)[i] = v; }
template<> __device__ __forceinline__ void stv<bf16 >(void* p, int i, float v){ ((bf16*)p)[i] = __float2bfloat16(v); }

template<typename T> __device__ __forceinline__ short ldbs(const void* p, int i);
template<> __device__ __forceinline__ short ldbs<bf16 >(const void* p, int i){ union{ bf16 b; short s; } u; u.b = ((const bf16*)p)[i]; return u.s; }
template<> __device__ __forceinline__ short ldbs<float>(const void* p, int i){ return f2bs(((const float*)p)[i]); }

struct Args {
    const void *h,*x,*v,*Win,*bin,*means,*betas,*Wo1,*bo1,*Wo2,*bo2,*Wsem,*bsem,*Wx,
               *Wp1,*bp1,*Wp2,*bp2,*Wn1,*bn1,*Wn2,*bn2,*Wv1,*bv1,*Wv2,*Wvm;
};

// ---- dtype detector ---------------------------------------------------------------
__global__ void k_detect(const void* means, int* flag){
    if (threadIdx.x == 0){
        float v = b2f(((const bf16*)means)[0]);
        flag[0] = (fabsf(v) > 1.0f || v != v) ? 1 : 0;   // 1 => inputs are float32
    }
}

// ---- per-node precompute (unchanged math; single kernel, runtime dtype branch) ----
template<typename T>
__device__ __forceinline__ void nodepre_body(const Args& A, short* __restrict__ U1,
                                             float* __restrict__ Aj, short* __restrict__ WxT,
                                             float* sh)
{
    int bn = blockIdx.x, t = threadIdx.x;
    sh[t] = ldv<T>(A.h, bn*64 + t);
    __syncthreads();
    float u1 = 0.f;
    for (int f = 0; f < 64; ++f) u1 += sh[f] * ldv<T>(A.Wo1, f*64 + t);
    U1[bn*64 + t] = f2bs(u1);
    if (t < 50){
        float a1 = 0.f;
        for (int f = 0; f < 64; ++f) a1 += sh[f] * ldv<T>(A.Win, f*50 + t);
        Aj[bn*64 + t] = a1;
    }
    int o = (bn*64 + t)*2;
    #pragma unroll
    for (int q = 0; q < 2; ++q){
        int oo = o + q;
        int hh = oo >> 14, rem = oo & 16383, n = rem >> 6, f = rem & 63;
        WxT[oo] = ldbs<T>(A.Wx, (4*f + hh)*256 + n);
    }
}

__global__ void __launch_bounds__(64) k_nodepre(Args A, const int* __restrict__ flag,
                                                short* __restrict__ U1, float* __restrict__ Aj,
                                                short* __restrict__ WxT)
{
    __shared__ float sh[64];
    if (flag[0]) nodepre_body<float>(A, U1, Aj, WxT, sh);
    else         nodepre_body<bf16 >(A, U1, Aj, WxT, sh);
}

// ---- fused SAKE layer: one block per node, 512 threads (8 waves) ------------------
// LDS plan (70400 B total -> 2 blocks/CU -> 16 waves/CU, 2x the R20 TLP):
//   edge-only staging (wo1t/wo2t) union'd with all post-edge arrays;
//   rbfh/mid per-wave scratch stored bf16 (identical rounding: MFMA A was bf16 anyway);
//   tree-softmax scratch (4KB, 16 barriers) replaced by shfl softmax (3 barriers).
struct SmemPost {
    __align__(16) float att[256][4];   // softmax weights           4096
    float part[2][256];                // h_e j-split partials      2048
    float red[768];                    // comb_sum                  3072
    float cn[256];                     // comb_norm                 1024
    float he[256];                     // h_e                       1024
    float fa[64];                      // f1 / f3                    256
    float fb[64];                      // f2 / f4(h_new)             256
    float mpart[8][64];                // split-K GEMV partials     2048
    float tmp[8][4];                   // softmax / dv scratch       128
};
struct SmemEdge {
    __align__(16) short wo1t[64*72];   // Wo1r^T [n][k pad72]       9216
    __align__(16) short wo2t[64*72];   // Wo2^T  [n][k pad72]       9216
};
struct Smem {
    __align__(16) bf16  e[256][72];    // edge features            36864
    __align__(16) float x4[256][4];    // xhat[3], d                4096
    float hi[64];
    float u2[64];
    float bo1v[64];
    float wl[64];
    float aivs[64];
    short wsem[256];
    __align__(16) short rbfh[8][4][72]; // per-wave rbf*h1 (bf16)   4608
    __align__(16) short mid[8][4][72];  // per-wave silu(o1) (bf16) 4608
    union { SmemEdge edge; SmemPost post; } u;  //                 18432
};

template<typename T>
__device__ __forceinline__ void sake_body(const Args& A,
        const short* __restrict__ U1w, const float* __restrict__ Ajw,
        const short* __restrict__ wxt, void* __restrict__ out, Smem& S)
{
    int bi = blockIdx.x;
    int b = bi >> 8, i = bi & 255;
    int tid = threadIdx.x, w = tid >> 6, lane = tid & 63;
    int lane15 = lane & 15, quad = lane >> 4;

    // ---- stage -------------------------------------------------------------------
    if (tid < 64)  S.hi[tid]   = ldv<T>(A.h, bi*64 + tid);
    if (tid < 256) S.wsem[tid] = ldbs<T>(A.Wsem, tid);
    #pragma unroll
    for (int q = 0; q < 8; ++q){
        int idx = q*512 + tid;           // 0..4095
        int n = idx >> 6, k = idx & 63;
        S.u.edge.wo2t[n*72 + k] = ldbs<T>(A.Wo2, k*64 + n);
        S.u.edge.wo1t[n*72 + k] = (k < 50) ? ldbs<T>(A.Wo1, (128+k)*64 + n) : (short)0;
    }
    if (lane >= 50){                     // zero-pad rbfh k in [50,64)
        #pragma unroll
        for (int pp = 0; pp < 4; ++pp) S.rbfh[w][pp][lane] = 0;
    }
    float xi0 = ldv<T>(A.x, bi*3+0), xi1 = ldv<T>(A.x, bi*3+1), xi2 = ldv<T>(A.x, bi*3+2);
    if (tid < 256){
        int j = tid;
        float dx = ldv<T>(A.x,(b*256+j)*3+0) - xi0;
        float dy = ldv<T>(A.x,(b*256+j)*3+1) - xi1;
        float dz = ldv<T>(A.x,(b*256+j)*3+2) - xi2;
        float dd = sqrtf(dx*dx + dy*dy + dz*dz + 1e-5f);
        float inv = 1.f/(dd + 1e-5f);
        S.x4[j][0] = dx*inv; S.x4[j][1] = dy*inv; S.x4[j][2] = dz*inv; S.x4[j][3] = dd;
    }
    __syncthreads();   // S.hi visible (fixes R20 race: waves>0 read s_hi pre-barrier)

    if (w == 0){
        float u2v = 0.f;
        for (int f = 0; f < 64; ++f) u2v += S.hi[f] * ldv<T>(A.Wo1, (64+f)*64 + lane);
        S.u2[lane]   = u2v;
        S.bo1v[lane] = ldv<T>(A.bo1, lane);
        S.wl[lane]   = ldv<T>(A.Wo1, 178*64 + lane);
    } else if (w == 1 && lane < 50){
        float av = 0.f;
        for (int f = 0; f < 64; ++f) av += S.hi[f] * ldv<T>(A.Win, (64+f)*50 + lane);
        S.aivs[lane] = av;
    }
    float muv = 0.f, bev = 0.f, binv = 0.f;
    if (lane < 50){
        muv = ldv<T>(A.means, lane); bev = ldv<T>(A.betas, lane); binv = ldv<T>(A.bin, lane);
    }
    __syncthreads();

    float aiv = (lane < 50) ? S.aivs[lane] : 0.f;
    float bo2c[4], u24[4], bo14[4], wl4[4];
    #pragma unroll
    for (int nf = 0; nf < 4; ++nf){
        bo2c[nf] = ldv<T>(A.bo2, nf*16 + lane15);
        u24[nf]  = S.u2[nf*16 + lane15];
        bo14[nf] = S.bo1v[nf*16 + lane15];
        wl4[nf]  = S.wl[nf*16 + lane15];
    }

    // ================= edge phase: 8 passes x (8 waves x 4 pairs) ==================
    for (int pass = 0; pass < 8; ++pass){
        int j0 = pass*32 + w*4;
        float dist[4];
        #pragma unroll
        for (int pp = 0; pp < 4; ++pp) dist[pp] = S.x4[j0+pp][3];

        if (lane < 50){
            #pragma unroll
            for (int pp = 0; pp < 4; ++pp){
                int j = j0 + pp;
                float h1 = Ajw[(b*256+j)*64 + lane] + aiv + binv;
                float dd = dist[pp];
                float cut = (dd < 5.f) ? 0.5f*(__cosf(dd*0.6283185307f) + 1.f) : 0.f;
                float ex = __expf(-dd) - muv;
                S.rbfh[w][pp][lane] = f2bs(cut * __expf(-bev*ex*ex) * h1);
            }
        }

        // ---- o1 via MFMA: [4 pairs x 64k] @ Wo1r ----
        bf16x8 ar[2];
        #pragma unroll
        for (int kk = 0; kk < 2; ++kk){
            bf16x8 av = (bf16x8){0,0,0,0,0,0,0,0};
            if (lane15 < 4) av = *(const bf16x8*)&S.rbfh[w][lane15][kk*32 + quad*8];
            ar[kk] = av;
        }
        #pragma unroll
        for (int nf = 0; nf < 4; ++nf){
            int n = nf*16 + lane15;
            f32x4 Co1 = (f32x4){0.f,0.f,0.f,0.f};
            if (quad == 0){
                #pragma unroll
                for (int r = 0; r < 4; ++r)
                    Co1[r] = bs2f(U1w[(b*256 + j0 + r)*64 + n]) + u24[nf] + bo14[nf] + dist[r]*wl4[nf];
            }
            bf16x8 b0 = *(const bf16x8*)&S.u.edge.wo1t[n*72 + quad*8];
            bf16x8 b1 = *(const bf16x8*)&S.u.edge.wo1t[n*72 + 32 + quad*8];
            Co1 = __builtin_amdgcn_mfma_f32_16x16x32_bf16(ar[0], b0, Co1, 0, 0, 0);
            Co1 = __builtin_amdgcn_mfma_f32_16x16x32_bf16(ar[1], b1, Co1, 0, 0, 0);
            if (quad == 0){
                #pragma unroll
                for (int r = 0; r < 4; ++r) S.mid[w][r][n] = f2bs(siluf(Co1[r]));
            }
        }

        // ---- o2 via MFMA: [4 pairs x 64k] @ Wo2 ----
        bf16x8 av2[2];
        #pragma unroll
        for (int kk = 0; kk < 2; ++kk){
            bf16x8 av = (bf16x8){0,0,0,0,0,0,0,0};
            if (lane15 < 4) av = *(const bf16x8*)&S.mid[w][lane15][kk*32 + quad*8];
            av2[kk] = av;
        }
        #pragma unroll
        for (int nf = 0; nf < 4; ++nf){
            int n = nf*16 + lane15;
            f32x4 Cc2 = (f32x4){bo2c[nf], bo2c[nf], bo2c[nf], bo2c[nf]};
            bf16x8 b0 = *(const bf16x8*)&S.u.edge.wo2t[n*72 + quad*8];
            bf16x8 b1 = *(const bf16x8*)&S.u.edge.wo2t[n*72 + 32 + quad*8];
            Cc2 = __builtin_amdgcn_mfma_f32_16x16x32_bf16(av2[0], b0, Cc2, 0, 0, 0);
            Cc2 = __builtin_amdgcn_mfma_f32_16x16x32_bf16(av2[1], b1, Cc2, 0, 0, 0);
            if (quad == 0){
                S.e[j0+0][n] = __float2bfloat16(Cc2[0]);
                S.e[j0+1][n] = __float2bfloat16(Cc2[1]);
                S.e[j0+2][n] = __float2bfloat16(Cc2[2]);
                S.e[j0+3][n] = __float2bfloat16(Cc2[3]);
            }
        }
    }
    __syncthreads();   // s_e visible; edge staging (union) dead from here on

    // ================= logits + shfl softmax (waves 0-3; 3 barriers) ===============
    float ex0 = 0.f, ex1 = 0.f, ex2 = 0.f, ex3 = 0.f;
    if (tid < 256){
        int j = tid;
        float a0 = ldv<T>(A.bsem,0), a1 = ldv<T>(A.bsem,1), a2 = ldv<T>(A.bsem,2), a3 = ldv<T>(A.bsem,3);
        const unsigned int* erow = (const unsigned int*)&S.e[j][0];   // 36 dwords/row
        for (int f2 = 0; f2 < 32; ++f2){
            unsigned int u0 = erow[f2];
            float e0 = lo16f(u0), e1 = hi16f(u0);
            a0 += e0*bs2f(S.wsem[f2*8+0]) + e1*bs2f(S.wsem[f2*8+4]);
            a1 += e0*bs2f(S.wsem[f2*8+1]) + e1*bs2f(S.wsem[f2*8+5]);
            a2 += e0*bs2f(S.wsem[f2*8+2]) + e1*bs2f(S.wsem[f2*8+6]);
            a3 += e0*bs2f(S.wsem[f2*8+3]) + e1*bs2f(S.wsem[f2*8+7]);
        }
        a0 = celu2(a0); a1 = celu2(a1); a2 = celu2(a2); a3 = celu2(a3);
        if (j == i){ a0 -= 1e5f; a1 -= 1e5f; a2 -= 1e5f; a3 -= 1e5f; }
        float m0 = a0, m1 = a1, m2 = a2, m3 = a3;
        #pragma unroll
        for (int off = 1; off < 64; off <<= 1){
            m0 = fmaxf(m0, __shfl_xor(m0, off)); m1 = fmaxf(m1, __shfl_xor(m1, off));
            m2 = fmaxf(m2, __shfl_xor(m2, off)); m3 = fmaxf(m3, __shfl_xor(m3, off));
        }
        if (lane == 0){
            S.u.post.tmp[w][0] = m0; S.u.post.tmp[w][1] = m1;
            S.u.post.tmp[w][2] = m2; S.u.post.tmp[w][3] = m3;
        }
        ex0 = a0; ex1 = a1; ex2 = a2; ex3 = a3;   // stash logits
    }
    __syncthreads();
    if (tid < 256){
        float m0 = fmaxf(fmaxf(S.u.post.tmp[0][0], S.u.post.tmp[1][0]), fmaxf(S.u.post.tmp[2][0], S.u.post.tmp[3][0]));
        float m1 = fmaxf(fmaxf(S.u.post.tmp[0][1], S.u.post.tmp[1][1]), fmaxf(S.u.post.tmp[2][1], S.u.post.tmp[3][1]));
        float m2 = fmaxf(fmaxf(S.u.post.tmp[0][2], S.u.post.tmp[1][2]), fmaxf(S.u.post.tmp[2][2], S.u.post.tmp[3][2]));
        float m3 = fmaxf(fmaxf(S.u.post.tmp[0][3], S.u.post.tmp[1][3]), fmaxf(S.u.post.tmp[2][3], S.u.post.tmp[3][3]));
        ex0 = __expf(ex0-m0); ex1 = __expf(ex1-m1); ex2 = __expf(ex2-m2); ex3 = __expf(ex3-m3);
        float s0 = ex0, s1 = ex1, s2 = ex2, s3 = ex3;
        #pragma unroll
        for (int off = 1; off < 64; off <<= 1){
            s0 += __shfl_xor(s0, off); s1 += __shfl_xor(s1, off);
            s2 += __shfl_xor(s2, off); s3 += __shfl_xor(s3, off);
        }
        if (lane == 0){
            S.u.post.tmp[4+w][0] = s0; S.u.post.tmp[4+w][1] = s1;
            S.u.post.tmp[4+w][2] = s2; S.u.post.tmp[4+w][3] = s3;
        }
    }
    __syncthreads();
    if (tid < 256){
        float s0 = S.u.post.tmp[4][0]+S.u.post.tmp[5][0]+S.u.post.tmp[6][0]+S.u.post.tmp[7][0];
        float s1 = S.u.post.tmp[4][1]+S.u.post.tmp[5][1]+S.u.post.tmp[6][1]+S.u.post.tmp[7][1];
        float s2 = S.u.post.tmp[4][2]+S.u.post.tmp[5][2]+S.u.post.tmp[6][2]+S.u.post.tmp[7][2];
        float s3 = S.u.post.tmp[4][3]+S.u.post.tmp[5][3]+S.u.post.tmp[6][3]+S.u.post.tmp[7][3];
        S.u.post.att[tid][0] = ex0/s0; S.u.post.att[tid][1] = ex1/s1;
        S.u.post.att[tid][2] = ex2/s2; S.u.post.att[tid][3] = ex3/s3;
    }
    __syncthreads();

    // ================= h_e[c] = sum_j e[j][f]*att[j][h], 2-way j-split =============
    {
        int c = tid & 255, jh = tid >> 8;
        int f_he = c >> 2, h_he = c & 3;
        float acc = 0.f;
        int j2 = jh*128;
        for (int q = 0; q < 128; ++q, ++j2)
            acc += b2f(S.e[j2][f_he]) * S.u.post.att[j2][h_he];
        S.u.post.part[jh][c] = acc;
    }
    __syncthreads();
    if (tid < 256) S.u.post.he[tid] = S.u.post.part[0][tid] + S.u.post.part[1][tid];

    // ================= x-mixing via att-factored MFMA (8 waves x 32 n) =============
    {
        const short* se_s = (const short*)S.e;   // row stride 72 shorts (144B, 16B-aligned)
        float ca[2][3];
        #pragma unroll
        for (int nf2 = 0; nf2 < 2; ++nf2){ ca[nf2][0]=0.f; ca[nf2][1]=0.f; ca[nf2][2]=0.f; }

        #pragma unroll
        for (int nf2 = 0; nf2 < 2; ++nf2){
            int n = w*32 + nf2*16 + lane15;
            bf16x8 Bh[4][2];
            #pragma unroll
            for (int hh = 0; hh < 4; ++hh){
                const short* bp = wxt + (hh*256 + n)*64 + quad*8;
                Bh[hh][0] = *(const bf16x8*)(bp);
                Bh[hh][1] = *(const bf16x8*)(bp + 32);
            }
            for (int mt = 0; mt < 16; ++mt){
                int jq = mt*16 + quad*4;
                f32x4 att4[4];
                #pragma unroll
                for (int r = 0; r < 4; ++r) att4[r] = *(const f32x4*)&S.u.post.att[jq + r][0];
                bf16x8 Af[2];
                #pragma unroll
                for (int ks = 0; ks < 2; ++ks)
                    Af[ks] = *(const bf16x8*)(se_s + (mt*16 + lane15)*72 + ks*32 + quad*8);
                float Pt[4] = {0.f, 0.f, 0.f, 0.f};
                #pragma unroll
                for (int hh = 0; hh < 4; ++hh){
                    f32x4 Cc = (f32x4){0.f,0.f,0.f,0.f};
                    Cc = __builtin_amdgcn_mfma_f32_16x16x32_bf16(Af[0], Bh[hh][0], Cc, 0, 0, 0);
                    Cc = __builtin_amdgcn_mfma_f32_16x16x32_bf16(Af[1], Bh[hh][1], Cc, 0, 0, 0);
                    #pragma unroll
                    for (int r = 0; r < 4; ++r) Pt[r] += att4[r][hh] * Cc[r];
                }
                #pragma unroll
                for (int r = 0; r < 4; ++r){
                    int j = jq + r;
                    float cf = tanhfast(Pt[r]);
                    f32x4 xh = *(const f32x4*)&S.x4[j][0];
                    ca[nf2][0] += cf*xh[0]; ca[nf2][1] += cf*xh[1]; ca[nf2][2] += cf*xh[2];
                }
            }
        }
        #pragma unroll
        for (int nf2 = 0; nf2 < 2; ++nf2){
            #pragma unroll
            for (int d = 0; d < 3; ++d){
                float vs = ca[nf2][d];
                vs += __shfl_xor(vs, 16);
                vs += __shfl_xor(vs, 32);
                if (quad == 0) S.u.post.red[(w*32 + nf2*16 + lane15)*3 + d] = vs;
            }
        }
    }
    __syncthreads();

    // ================= final per-node MLPs: split-K over 8 waves ===================
    const float sc = 1.f/256.f;
    if (tid < 256){
        float c0 = S.u.post.red[tid*3+0]*sc, c1 = S.u.post.red[tid*3+1]*sc, c2 = S.u.post.red[tid*3+2]*sc;
        S.u.post.cn[tid] = c0*c0 + c1*c1 + c2*c2;
    }
    __syncthreads();

    // p1: K=256
    {
        float acc = 0.f;
        int c0 = w*32;
        for (int c = c0; c < c0+32; ++c) acc += S.u.post.cn[c] * ldv<T>(A.Wp1, c*64 + lane);
        S.u.post.mpart[w][lane] = acc;
    }
    __syncthreads();
    if (tid < 64){
        float acc = ldv<T>(A.bp1, tid);
        #pragma unroll
        for (int q = 0; q < 8; ++q) acc += S.u.post.mpart[q][tid];
        S.u.post.fa[tid] = siluf(acc);
    }
    __syncthreads();
    // p2: K=64
    {
        float acc = 0.f;
        int k0 = w*8;
        #pragma unroll
        for (int k = 0; k < 8; ++k) acc += S.u.post.fa[k0+k] * ldv<T>(A.Wp2, (k0+k)*64 + lane);
        S.u.post.mpart[w][lane] = acc;
    }
    __syncthreads();
    if (tid < 64){
        float acc = ldv<T>(A.bp2, tid);
        #pragma unroll
        for (int q = 0; q < 8; ++q) acc += S.u.post.mpart[q][tid];
        S.u.post.fb[tid] = siluf(acc);
    }
    __syncthreads();
    // n1: K=384 (64 h | 256 h_e | 64 f2)
    {
        float acc = 0.f;
        int r0 = w*48;
        for (int r = r0; r < r0+48; ++r){
            float xv = (r < 64) ? S.hi[r] : (r < 320) ? S.u.post.he[r-64] : S.u.post.fb[r-320];
            acc += xv * ldv<T>(A.Wn1, r*64 + lane);
        }
        S.u.post.mpart[w][lane] = acc;
    }
    __syncthreads();
    if (tid < 64){
        float acc = ldv<T>(A.bn1, tid);
        #pragma unroll
        for (int q = 0; q < 8; ++q) acc += S.u.post.mpart[q][tid];
        S.u.post.fa[tid] = siluf(acc);      // f3 (f1 dead)
    }
    __syncthreads();
    // n2: K=64
    {
        float acc = 0.f;
        int k0 = w*8;
        #pragma unroll
        for (int k = 0; k < 8; ++k) acc += S.u.post.fa[k0+k] * ldv<T>(A.Wn2, (k0+k)*64 + lane);
        S.u.post.mpart[w][lane] = acc;
    }
    __syncthreads();
    if (tid < 64){
        float acc = ldv<T>(A.bn2, tid);
        #pragma unroll
        for (int q = 0; q < 8; ++q) acc += S.u.post.mpart[q][tid];
        float hn = S.hi[tid] + siluf(acc);
        stv<T>(out, bi*64 + tid, hn);
        S.u.post.fb[tid] = hn;              // f4 = h_new (f2 dead)
    }
    __syncthreads();
    // v1: K=64
    {
        float acc = 0.f;
        int k0 = w*8;
        #pragma unroll
        for (int k = 0; k < 8; ++k) acc += S.u.post.fb[k0+k] * ldv<T>(A.Wv1, (k0+k)*64 + lane);
        S.u.post.mpart[w][lane] = acc;
    }
    __syncthreads();
    float vscale = 0.f;
    if (tid < 64){
        float acc = ldv<T>(A.bv1, tid);
        #pragma unroll
        for (int q = 0; q < 8; ++q) acc += S.u.post.mpart[q][tid];
        float term = siluf(acc) * ldv<T>(A.Wv2, tid);
        #pragma unroll
        for (int off = 1; off < 64; off <<= 1) term += __shfl_xor(term, off);
        vscale = 2.f / (1.f + __expf(-term));
    }
    // dv partials on waves 0..3 (independent of v1 combine above)
    if (w < 4){
        int c = w*64 + lane;
        float wv = ldv<T>(A.Wvm, c);
        float d0 = S.u.post.red[c*3+0]*sc*wv;
        float d1 = S.u.post.red[c*3+1]*sc*wv;
        float d2 = S.u.post.red[c*3+2]*sc*wv;
        #pragma unroll
        for (int off = 1; off < 64; off <<= 1){
            d0 += __shfl_xor(d0, off); d1 += __shfl_xor(d1, off); d2 += __shfl_xor(d2, off);
        }
        if (lane == 0){ S.u.post.tmp[w][0] = d0; S.u.post.tmp[w][1] = d1; S.u.post.tmp[w][2] = d2; }
    }
    __syncthreads();
    if (tid < 3){
        float dv = S.u.post.tmp[0][tid] + S.u.post.tmp[1][tid] + S.u.post.tmp[2][tid] + S.u.post.tmp[3][tid];
        float vn = dv + vscale * ldv<T>(A.v, bi*3 + tid);
        float xn = ldv<T>(A.x, bi*3 + tid) + vn;
        stv<T>(out, 32768 + bi*3 + tid, xn);  // x_new
        stv<T>(out, 34304 + bi*3 + tid, vn);  // v_new
    }
}

__global__ void __launch_bounds__(512, 4) k_sake(Args A, const int* __restrict__ flag,
                                                 const short* __restrict__ U1w,
                                                 const float* __restrict__ Ajw,
                                                 const short* __restrict__ wxt,
                                                 void* __restrict__ out)
{
    __shared__ Smem S;
    if (flag[0]) sake_body<float>(A, U1w, Ajw, wxt, out, S);
    else         sake_body<bf16 >(A, U1w, Ajw, wxt, out, S);
}

extern "C" void kernel_launch(void* const* d_in, const int* in_sizes, int n_in,
                              void* d_out, int out_size, void* d_ws, size_t ws_size,
                              hipStream_t stream)
{
    Args A;
    A.h     = d_in[0];  A.x     = d_in[1];  A.v     = d_in[2];
    A.Win   = d_in[3];  A.bin   = d_in[4];  A.means = d_in[5];  A.betas = d_in[6];
    A.Wo1   = d_in[7];  A.bo1   = d_in[8];  A.Wo2   = d_in[9];  A.bo2   = d_in[10];
    A.Wsem  = d_in[11]; A.bsem  = d_in[12]; A.Wx    = d_in[13];
    A.Wp1   = d_in[14]; A.bp1   = d_in[15]; A.Wp2   = d_in[16]; A.bp2   = d_in[17];
    A.Wn1   = d_in[18]; A.bn1   = d_in[19]; A.Wn2   = d_in[20]; A.bn2   = d_in[21];
    A.Wv1   = d_in[22]; A.bv1   = d_in[23]; A.Wv2   = d_in[24]; A.Wvm   = d_in[25];

    // ws layout: flag 64B | U1 bf16 512x64 (64KB) | Aj f32 512x64 (128KB) | WxH bf16 4x256x64 (128KB)
    int*   flag = (int*)d_ws;
    short* U1b  = (short*)((char*)d_ws + 64);
    float* Aj   = (float*)((char*)d_ws + 64 + 65536);
    short* WxT  = (short*)((char*)d_ws + 64 + 65536 + 131072);

    k_detect<<<1, 64, 0, stream>>>(A.means, flag);
    k_nodepre<<<NNODE, 64, 0, stream>>>(A, flag, U1b, Aj, WxT);
    k_sake<<<NNODE, 512, 0, stream>>>(A, flag, U1b, Aj, WxT, d_out);
}

// Round 2
// 180.077 us; speedup vs baseline: 1.1994x; 1.1200x over previous
//
#include <hip/hip_runtime.h>
#include <hip/hip_bf16.h>

typedef __hip_bfloat16 bf16;
typedef __attribute__((ext_vector_type(8))) short bf16x8;
typedef __attribute__((ext_vector_type(4))) short s16x4;
typedef __attribute__((ext_vector_type(4))) float f32x4;

#define NNODE 512   // B*N

__device__ __forceinline__ float b2f(bf16 v){ return __bfloat162float(v); }
__device__ __forceinline__ float siluf(float x){ return x / (1.f + __expf(-x)); }
__device__ __forceinline__ float tanhfast(float x){ return 1.f - 2.f/(__expf(2.f*x)+1.f); }
__device__ __forceinline__ float celu2(float x){ return x > 0.f ? x : 2.f*(__expf(0.5f*x)-1.f); }
__device__ __forceinline__ float bs2f(short v){ union{unsigned int i; float f;} t; t.i = ((unsigned int)(unsigned short)v) << 16; return t.f; }
__device__ __forceinline__ short f2bs(float x){ union{ bf16 b; short s; } u; u.b = __float2bfloat16(x); return u.s; }
__device__ __forceinline__ float lo16f(unsigned int u){ union{unsigned int i; float f;} t; t.i = u<<16; return t.f; }
__device__ __forceinline__ float hi16f(unsigned int u){ union{unsigned int i; float f;} t; t.i = u & 0xffff0000u; return t.f; }

// ---- dtype-polymorphic scalar load/store -------------------------------------------
template<typename T> __device__ __forceinline__ float ldv(const void* p, int i);
template<> __device__ __forceinline__ float ldv<float>(const void* p, int i){ return ((const float*)p)[i]; }
template<> __device__ __forceinline__ float ldv<bf16 >(const void* p, int i){ return b2f(((const bf16*)p)[i]); }

template<typename T> __device__ __forceinline__ void stv(void* p, int i, float v);
template<> __device__ __forceinline__ void stv<float>(void* p, int i, float v){ ((float*)p)[i] = v; }
template<> __device__ __forceinline__ void stv<bf16 >(void* p, int i, float v){ ((bf16*)p)[i] = __float2bfloat16(v); }

template<typename T> __device__ __forceinline__ short ldbs(const void* p, int i);
template<> __device__ __forceinline__ short ldbs<bf16 >(const void* p, int i){ union{ bf16 b; short s; } u; u.b = ((const bf16*)p)[i]; return u.s; }
template<> __device__ __forceinline__ short ldbs<float>(const void* p, int i){ return f2bs(((const float*)p)[i]); }

struct Args {
    const void *h,*x,*v,*Win,*bin,*means,*betas,*Wo1,*bo1,*Wo2,*bo2,*Wsem,*bsem,*Wx,
               *Wp1,*bp1,*Wp2,*bp2,*Wn1,*bn1,*Wn2,*bn2,*Wv1,*bv1,*Wv2,*Wvm;
};

// inline dtype detect (removes k_detect launch): rbf_means[0] ~ 0.0067 as f32;
// read as bf16 it is tiny; the low half of an f32 read as bf16 is huge/NaN.
__device__ __forceinline__ bool detect_f32(const void* means){
    float v = b2f(((const bf16*)means)[0]);
    return (fabsf(v) > 1.0f || v != v);
}

// ---- per-node precompute: 256 threads, 4-way split-K (was 64 threads, latency-bound)
template<typename T>
__device__ __forceinline__ void nodepre_body(const Args& A, short* __restrict__ U1,
                                             float* __restrict__ Aj, short* __restrict__ WxT,
                                             float* sh, float (*p1)[64], float (*p2)[64])
{
    int bn = blockIdx.x, tid = threadIdx.x;
    int t = tid & 63, ks = tid >> 6;
    if (tid < 64) sh[tid] = ldv<T>(A.h, bn*64 + tid);
    __syncthreads();
    float a1 = 0.f;
    #pragma unroll
    for (int q = 0; q < 16; ++q){
        int f = ks*16 + q;
        a1 += sh[f] * ldv<T>(A.Wo1, f*64 + t);
    }
    p1[ks][t] = a1;
    if (t < 50){
        float a2 = 0.f;
        #pragma unroll
        for (int q = 0; q < 16; ++q){
            int f = ks*16 + q;
            a2 += sh[f] * ldv<T>(A.Win, f*50 + t);
        }
        p2[ks][t] = a2;
    }
    if (tid < 128){
        int oo = bn*128 + tid;
        int hh = oo >> 14, rem = oo & 16383, n = rem >> 6, f = oo & 63;
        WxT[oo] = ldbs<T>(A.Wx, (4*f + hh)*256 + n);
    }
    __syncthreads();
    if (tid < 64){
        U1[bn*64 + tid] = f2bs(p1[0][tid] + p1[1][tid] + p1[2][tid] + p1[3][tid]);
        float av = (tid < 50) ? (p2[0][tid] + p2[1][tid] + p2[2][tid] + p2[3][tid]) : 0.f;
        Aj[bn*64 + tid] = av;   // rows 50..63 zeroed: edge phase vector-loads full strips
    }
}

__global__ void __launch_bounds__(256) k_nodepre(Args A, short* __restrict__ U1,
                                                 float* __restrict__ Aj, short* __restrict__ WxT)
{
    __shared__ float sh[64];
    __shared__ float p1[4][64];
    __shared__ float p2[4][64];
    if (detect_f32(A.means)) nodepre_body<float>(A, U1, Aj, WxT, sh, p1, p2);
    else                     nodepre_body<bf16 >(A, U1, Aj, WxT, sh, p1, p2);
}

// ---- fused SAKE layer: one block per node, 512 threads (8 waves) ------------------
// R2: transposed edge GEMMs (A=weight^T, B=data) -> rbf built directly in B-fragment
// registers (no rbfh LDS, 16 pairs/pass, 32 MFMA/wave vs 128); logits via MFMA;
// h_e dword-vectorized 4-way j-split; xmix mt-fused (att4/Af loaded once per mt).
struct SmemPost {
    __align__(16) float att[256][4];   // logits -> softmax weights  4096
    float part[4][256];                // h_e j-split partials       4096
    float red[768];                    // comb_sum                   3072
    float cn[256];                     // comb_norm                  1024
    float he[256];                     // h_e                        1024
    float fa[64];                      // f1/f3                       256
    float fb[64];                      // f2/f4                       256
    float mpart[8][64];                // split-K GEMV partials      2048
    float tmp[8][4];                   // softmax / dv scratch        128
};                                     // total 16000
struct Smem {
    __align__(16) bf16  e[256][72];    // edge features             36864
    __align__(16) float x4[256][4];    // xhat[3], d                 4096
    float hi[64];                      //                             256
    float ub[64];                      // u2 + bo1                    256
    float wl[64];                      // Wo1 dist row                256
    __align__(16) float kc[64][4];     // mu, beta, bin, aiv         1024
    short wsem[256];                   //                             512
    __align__(16) short wo1t[64*72];   // Wo1r^T [n][k pad72]        9216
    __align__(16) short wo2t[64*72];   // Wo2^T  [n][k pad72]        9216
    union {
        SmemPost post;                 // post-edge                 16000
        __align__(16) short mid[8][16][72]; // edge o1 scratch      18432
    } u;
};                                     // total 80128 -> 2 blocks/CU

template<typename T>
__device__ __forceinline__ void sake_body(const Args& A,
        const short* __restrict__ U1w, const float* __restrict__ Ajw,
        const short* __restrict__ wxt, void* __restrict__ out, Smem& S)
{
    int bi = blockIdx.x;
    int b = bi >> 8, i = bi & 255;
    int tid = threadIdx.x, w = tid >> 6, lane = tid & 63;
    int lane15 = lane & 15, quad = lane >> 4;

    // ---- stage -------------------------------------------------------------------
    if (tid < 64)  S.hi[tid]   = ldv<T>(A.h, bi*64 + tid);
    if (tid < 256) S.wsem[tid] = ldbs<T>(A.Wsem, tid);
    if (tid < 64){
        bool kv = tid < 50;
        S.kc[tid][0] = kv ? ldv<T>(A.means, tid) : 0.f;
        S.kc[tid][1] = kv ? ldv<T>(A.betas, tid) : 0.f;
        S.kc[tid][2] = kv ? ldv<T>(A.bin,   tid) : 0.f;
        S.kc[tid][3] = 0.f;
    }
    #pragma unroll
    for (int q = 0; q < 8; ++q){
        int idx = q*512 + tid;           // 0..4095
        int n = idx >> 6, k = idx & 63;
        S.wo2t[n*72 + k] = ldbs<T>(A.Wo2, k*64 + n);
        S.wo1t[n*72 + k] = (k < 50) ? ldbs<T>(A.Wo1, (128+k)*64 + n) : (short)0;
    }
    float xi0 = ldv<T>(A.x, bi*3+0), xi1 = ldv<T>(A.x, bi*3+1), xi2 = ldv<T>(A.x, bi*3+2);
    if (tid < 256){
        int j = tid;
        float dx = ldv<T>(A.x,(b*256+j)*3+0) - xi0;
        float dy = ldv<T>(A.x,(b*256+j)*3+1) - xi1;
        float dz = ldv<T>(A.x,(b*256+j)*3+2) - xi2;
        float dd = sqrtf(dx*dx + dy*dy + dz*dz + 1e-5f);
        float inv = 1.f/(dd + 1e-5f);
        S.x4[j][0] = dx*inv; S.x4[j][1] = dy*inv; S.x4[j][2] = dz*inv; S.x4[j][3] = dd;
    }
    __syncthreads();   // hi/x4/kc[0..2]/weights visible

    if (w == 0){
        float u2v = 0.f;
        for (int f = 0; f < 64; ++f) u2v += S.hi[f] * ldv<T>(A.Wo1, (64+f)*64 + lane);
        S.ub[lane] = u2v + ldv<T>(A.bo1, lane);
        S.wl[lane] = ldv<T>(A.Wo1, 178*64 + lane);
    } else if (w == 1 && lane < 50){
        float av = 0.f;
        for (int f = 0; f < 64; ++f) av += S.hi[f] * ldv<T>(A.Win, (64+f)*50 + lane);
        S.kc[lane][3] = av;
    }
    __syncthreads();   // ub/wl/aiv visible

    // per-lane hoisted C-init constants: rows m = nf*16 + quad*4 + r
    float ubr[16], wlr[16], bo2r[16];
    #pragma unroll
    for (int nf = 0; nf < 4; ++nf){
        #pragma unroll
        for (int r = 0; r < 4; ++r){
            int m = nf*16 + quad*4 + r;
            ubr[nf*4+r]  = S.ub[m];
            wlr[nf*4+r]  = S.wl[m];
            bo2r[nf*4+r] = ldv<T>(A.bo2, m);
        }
    }

    // ================= edge phase: 2 passes x (8 waves x 16 pairs) =================
    // o1^T:  mid[pair][n] = sum_k Wo1r[k][n] * rbfh[pair][k]   (A=wo1t, B=rbf-in-reg)
    // o2^T:  e[pair][n2]  = sum_n Wo2[n][n2] * mid[pair][n]    (A=wo2t, B=mid b128)
    for (int pass = 0; pass < 2; ++pass){
        int j = pass*128 + w*16 + lane15;    // this lane's pair
        float dd  = S.x4[j][3];
        float cut = (dd < 5.f) ? 0.5f*(__cosf(dd*0.6283185307f) + 1.f) : 0.f;
        float ed  = __expf(-dd);
        const float* ajp = Ajw + (b*256 + j)*64;
        bf16x8 Brb[2];
        #pragma unroll
        for (int s = 0; s < 2; ++s){
            int kb = s*32 + quad*8;
            f32x4 a0 = *(const f32x4*)(ajp + kb);
            f32x4 a1 = *(const f32x4*)(ajp + kb + 4);
            bf16x8 bv;
            #pragma unroll
            for (int i2 = 0; i2 < 8; ++i2){
                int k = kb + i2;
                f32x4 kcv = *(const f32x4*)&S.kc[k][0];   // mu, beta, bin, aiv
                float aj = (i2 < 4) ? a0[i2] : a1[i2-4];
                float h1 = aj + kcv[3] + kcv[2];
                float ex = ed - kcv[0];
                float val = cut * __expf(-kcv[1]*ex*ex) * h1;
                bv[i2] = (k < 50) ? f2bs(val) : (short)0;
            }
            Brb[s] = bv;
        }
        const short* u1p = U1w + (b*256 + j)*64;
        #pragma unroll
        for (int nf = 0; nf < 4; ++nf){
            const short* wp = S.wo1t + (nf*16 + lane15)*72;
            bf16x8 A0 = *(const bf16x8*)(wp + quad*8);
            bf16x8 A1 = *(const bf16x8*)(wp + 32 + quad*8);
            s16x4 u4 = *(const s16x4*)(u1p + nf*16 + quad*4);
            f32x4 C;
            #pragma unroll
            for (int r = 0; r < 4; ++r)
                C[r] = bs2f(u4[r]) + ubr[nf*4+r] + dd*wlr[nf*4+r];
            C = __builtin_amdgcn_mfma_f32_16x16x32_bf16(A0, Brb[0], C, 0, 0, 0);
            C = __builtin_amdgcn_mfma_f32_16x16x32_bf16(A1, Brb[1], C, 0, 0, 0);
            s16x4 m4;
            #pragma unroll
            for (int r = 0; r < 4; ++r) m4[r] = f2bs(siluf(C[r]));
            *(s16x4*)&S.u.mid[w][lane15][nf*16 + quad*4] = m4;
        }
        // same-wave LDS RAW: compiler inserts lgkmcnt (proven pattern from R1 s_mid)
        bf16x8 Bm0 = *(const bf16x8*)&S.u.mid[w][lane15][quad*8];
        bf16x8 Bm1 = *(const bf16x8*)&S.u.mid[w][lane15][32 + quad*8];
        #pragma unroll
        for (int nf = 0; nf < 4; ++nf){
            const short* wp = S.wo2t + (nf*16 + lane15)*72;
            bf16x8 A0 = *(const bf16x8*)(wp + quad*8);
            bf16x8 A1 = *(const bf16x8*)(wp + 32 + quad*8);
            f32x4 C = (f32x4){bo2r[nf*4+0], bo2r[nf*4+1], bo2r[nf*4+2], bo2r[nf*4+3]};
            C = __builtin_amdgcn_mfma_f32_16x16x32_bf16(A0, Bm0, C, 0, 0, 0);
            C = __builtin_amdgcn_mfma_f32_16x16x32_bf16(A1, Bm1, C, 0, 0, 0);
            s16x4 e4;
            #pragma unroll
            for (int r = 0; r < 4; ++r) e4[r] = f2bs(C[r]);
            *(s16x4*)&((short*)S.e)[j*72 + nf*16 + quad*4] = e4;
        }
    }
    __syncthreads();   // s_e visible; edge union (mid) dead from here

    // ================= semantic logits via MFMA (2 j-tiles per wave) ===============
    {
        bf16x8 Bs[2];
        #pragma unroll
        for (int ks = 0; ks < 2; ++ks){
            bf16x8 bv = (bf16x8){0,0,0,0,0,0,0,0};
            if (lane15 < 4){
                #pragma unroll
                for (int i2 = 0; i2 < 8; ++i2)
                    bv[i2] = S.wsem[(ks*32 + quad*8 + i2)*4 + lane15];
            }
            Bs[ks] = bv;
        }
        float bsv = (lane15 < 4) ? ldv<T>(A.bsem, lane15) : 0.f;
        #pragma unroll
        for (int t2 = 0; t2 < 2; ++t2){
            int jt = w*2 + t2;
            const short* ep = (const short*)S.e + (jt*16 + lane15)*72;
            bf16x8 A0 = *(const bf16x8*)(ep + quad*8);
            bf16x8 A1 = *(const bf16x8*)(ep + 32 + quad*8);
            f32x4 C = (f32x4){bsv, bsv, bsv, bsv};
            C = __builtin_amdgcn_mfma_f32_16x16x32_bf16(A0, Bs[0], C, 0, 0, 0);
            C = __builtin_amdgcn_mfma_f32_16x16x32_bf16(A1, Bs[1], C, 0, 0, 0);
            if (lane15 < 4){
                #pragma unroll
                for (int r = 0; r < 4; ++r){
                    int jr = jt*16 + quad*4 + r;
                    float lv = celu2(C[r]);
                    if (jr == i) lv -= 1e5f;
                    S.u.post.att[jr][lane15] = lv;
                }
            }
        }
    }
    __syncthreads();

    // ================= softmax over j (4 heads; shfl + 8-wave combine) =============
    float ex0 = 0.f, ex1 = 0.f, ex2 = 0.f, ex3 = 0.f;
    if (tid < 256){
        float l0 = S.u.post.att[tid][0], l1 = S.u.post.att[tid][1];
        float l2 = S.u.post.att[tid][2], l3 = S.u.post.att[tid][3];
        float m0 = l0, m1 = l1, m2 = l2, m3 = l3;
        #pragma unroll
        for (int off = 1; off < 64; off <<= 1){
            m0 = fmaxf(m0, __shfl_xor(m0, off)); m1 = fmaxf(m1, __shfl_xor(m1, off));
            m2 = fmaxf(m2, __shfl_xor(m2, off)); m3 = fmaxf(m3, __shfl_xor(m3, off));
        }
        if (lane == 0){
            S.u.post.tmp[w][0] = m0; S.u.post.tmp[w][1] = m1;
            S.u.post.tmp[w][2] = m2; S.u.post.tmp[w][3] = m3;
        }
        ex0 = l0; ex1 = l1; ex2 = l2; ex3 = l3;
    }
    __syncthreads();
    if (tid < 256){
        float m0 = fmaxf(fmaxf(S.u.post.tmp[0][0], S.u.post.tmp[1][0]), fmaxf(S.u.post.tmp[2][0], S.u.post.tmp[3][0]));
        float m1 = fmaxf(fmaxf(S.u.post.tmp[0][1], S.u.post.tmp[1][1]), fmaxf(S.u.post.tmp[2][1], S.u.post.tmp[3][1]));
        float m2 = fmaxf(fmaxf(S.u.post.tmp[0][2], S.u.post.tmp[1][2]), fmaxf(S.u.post.tmp[2][2], S.u.post.tmp[3][2]));
        float m3 = fmaxf(fmaxf(S.u.post.tmp[0][3], S.u.post.tmp[1][3]), fmaxf(S.u.post.tmp[2][3], S.u.post.tmp[3][3]));
        ex0 = __expf(ex0-m0); ex1 = __expf(ex1-m1); ex2 = __expf(ex2-m2); ex3 = __expf(ex3-m3);
        float s0 = ex0, s1 = ex1, s2 = ex2, s3 = ex3;
        #pragma unroll
        for (int off = 1; off < 64; off <<= 1){
            s0 += __shfl_xor(s0, off); s1 += __shfl_xor(s1, off);
            s2 += __shfl_xor(s2, off); s3 += __shfl_xor(s3, off);
        }
        if (lane == 0){
            S.u.post.tmp[4+w][0] = s0; S.u.post.tmp[4+w][1] = s1;
            S.u.post.tmp[4+w][2] = s2; S.u.post.tmp[4+w][3] = s3;
        }
    }
    __syncthreads();
    if (tid < 256){
        float s0 = S.u.post.tmp[4][0]+S.u.post.tmp[5][0]+S.u.post.tmp[6][0]+S.u.post.tmp[7][0];
        float s1 = S.u.post.tmp[4][1]+S.u.post.tmp[5][1]+S.u.post.tmp[6][1]+S.u.post.tmp[7][1];
        float s2 = S.u.post.tmp[4][2]+S.u.post.tmp[5][2]+S.u.post.tmp[6][2]+S.u.post.tmp[7][2];
        float s3 = S.u.post.tmp[4][3]+S.u.post.tmp[5][3]+S.u.post.tmp[6][3]+S.u.post.tmp[7][3];
        S.u.post.att[tid][0] = ex0/s0; S.u.post.att[tid][1] = ex1/s1;
        S.u.post.att[tid][2] = ex2/s2; S.u.post.att[tid][3] = ex3/s3;
    }
    __syncthreads();

    // ================= h_e: dword-packed e reads, 4-way j-split ====================
    {
        int cg = tid & 127, js = tid >> 7;
        int fp = cg >> 2, hh = cg & 3;
        float acc0 = 0.f, acc1 = 0.f;
        const unsigned int* ep = (const unsigned int*)S.e;   // row stride 36 dwords
        for (int jj = 0; jj < 64; ++jj){
            int j = js*64 + jj;
            unsigned int u = ep[j*36 + fp];
            float a = S.u.post.att[j][hh];
            acc0 += lo16f(u)*a; acc1 += hi16f(u)*a;
        }
        S.u.post.part[js][8*fp + hh]     = acc0;
        S.u.post.part[js][8*fp + 4 + hh] = acc1;
    }
    __syncthreads();
    if (tid < 256)
        S.u.post.he[tid] = S.u.post.part[0][tid] + S.u.post.part[1][tid]
                         + S.u.post.part[2][tid] + S.u.post.part[3][tid];

    // ================= x-mixing: mt-fused att-factored MFMA ========================
    {
        const short* se_s = (const short*)S.e;   // row stride 72 shorts
        bf16x8 Bh[2][4][2];                      // [nf2][h][ks] fully hoisted
        #pragma unroll
        for (int nf2 = 0; nf2 < 2; ++nf2){
            int n = w*32 + nf2*16 + lane15;
            #pragma unroll
            for (int hh = 0; hh < 4; ++hh){
                const short* bp = wxt + (hh*256 + n)*64 + quad*8;
                Bh[nf2][hh][0] = *(const bf16x8*)(bp);
                Bh[nf2][hh][1] = *(const bf16x8*)(bp + 32);
            }
        }
        float ca[2][3];
        #pragma unroll
        for (int nf2 = 0; nf2 < 2; ++nf2){ ca[nf2][0]=0.f; ca[nf2][1]=0.f; ca[nf2][2]=0.f; }

        for (int mt = 0; mt < 16; ++mt){
            int jq = mt*16 + quad*4;
            f32x4 att4[4];
            #pragma unroll
            for (int r = 0; r < 4; ++r) att4[r] = *(const f32x4*)&S.u.post.att[jq + r][0];
            bf16x8 Af[2];
            #pragma unroll
            for (int ks = 0; ks < 2; ++ks)
                Af[ks] = *(const bf16x8*)(se_s + (mt*16 + lane15)*72 + ks*32 + quad*8);
            #pragma unroll
            for (int nf2 = 0; nf2 < 2; ++nf2){
                float Pt[4] = {0.f, 0.f, 0.f, 0.f};
                #pragma unroll
                for (int hh = 0; hh < 4; ++hh){
                    f32x4 Cc = (f32x4){0.f,0.f,0.f,0.f};
                    Cc = __builtin_amdgcn_mfma_f32_16x16x32_bf16(Af[0], Bh[nf2][hh][0], Cc, 0, 0, 0);
                    Cc = __builtin_amdgcn_mfma_f32_16x16x32_bf16(Af[1], Bh[nf2][hh][1], Cc, 0, 0, 0);
                    #pragma unroll
                    for (int r = 0; r < 4; ++r) Pt[r] += att4[r][hh] * Cc[r];
                }
                #pragma unroll
                for (int r = 0; r < 4; ++r){
                    int j = jq + r;
                    float cf = tanhfast(Pt[r]);
                    f32x4 xh = *(const f32x4*)&S.x4[j][0];
                    ca[nf2][0] += cf*xh[0]; ca[nf2][1] += cf*xh[1]; ca[nf2][2] += cf*xh[2];
                }
            }
        }
        #pragma unroll
        for (int nf2 = 0; nf2 < 2; ++nf2){
            #pragma unroll
            for (int d = 0; d < 3; ++d){
                float vs = ca[nf2][d];
                vs += __shfl_xor(vs, 16);
                vs += __shfl_xor(vs, 32);
                if (quad == 0) S.u.post.red[(w*32 + nf2*16 + lane15)*3 + d] = vs;
            }
        }
    }
    __syncthreads();

    // ================= final per-node MLPs: split-K over 8 waves ===================
    const float sc = 1.f/256.f;
    if (tid < 256){
        float c0 = S.u.post.red[tid*3+0]*sc, c1 = S.u.post.red[tid*3+1]*sc, c2 = S.u.post.red[tid*3+2]*sc;
        S.u.post.cn[tid] = c0*c0 + c1*c1 + c2*c2;
    }
    __syncthreads();

    // p1: K=256
    {
        float acc = 0.f;
        int c0 = w*32;
        for (int c = c0; c < c0+32; ++c) acc += S.u.post.cn[c] * ldv<T>(A.Wp1, c*64 + lane);
        S.u.post.mpart[w][lane] = acc;
    }
    __syncthreads();
    if (tid < 64){
        float acc = ldv<T>(A.bp1, tid);
        #pragma unroll
        for (int q = 0; q < 8; ++q) acc += S.u.post.mpart[q][tid];
        S.u.post.fa[tid] = siluf(acc);
    }
    __syncthreads();
    // p2: K=64
    {
        float acc = 0.f;
        int k0 = w*8;
        #pragma unroll
        for (int k = 0; k < 8; ++k) acc += S.u.post.fa[k0+k] * ldv<T>(A.Wp2, (k0+k)*64 + lane);
        S.u.post.mpart[w][lane] = acc;
    }
    __syncthreads();
    if (tid < 64){
        float acc = ldv<T>(A.bp2, tid);
        #pragma unroll
        for (int q = 0; q < 8; ++q) acc += S.u.post.mpart[q][tid];
        S.u.post.fb[tid] = siluf(acc);
    }
    __syncthreads();
    // n1: K=384 (64 h | 256 h_e | 64 f2)
    {
        float acc = 0.f;
        int r0 = w*48;
        for (int r = r0; r < r0+48; ++r){
            float xv = (r < 64) ? S.hi[r] : (r < 320) ? S.u.post.he[r-64] : S.u.post.fb[r-320];
            acc += xv * ldv<T>(A.Wn1, r*64 + lane);
        }
        S.u.post.mpart[w][lane] = acc;
    }
    __syncthreads();
    if (tid < 64){
        float acc = ldv<T>(A.bn1, tid);
        #pragma unroll
        for (int q = 0; q < 8; ++q) acc += S.u.post.mpart[q][tid];
        S.u.post.fa[tid] = siluf(acc);      // f3
    }
    __syncthreads();
    // n2: K=64
    {
        float acc = 0.f;
        int k0 = w*8;
        #pragma unroll
        for (int k = 0; k < 8; ++k) acc += S.u.post.fa[k0+k] * ldv<T>(A.Wn2, (k0+k)*64 + lane);
        S.u.post.mpart[w][lane] = acc;
    }
    __syncthreads();
    if (tid < 64){
        float acc = ldv<T>(A.bn2, tid);
        #pragma unroll
        for (int q = 0; q < 8; ++q) acc += S.u.post.mpart[q][tid];
        float hn = S.hi[tid] + siluf(acc);
        stv<T>(out, bi*64 + tid, hn);
        S.u.post.fb[tid] = hn;              // f4 = h_new
    }
    __syncthreads();
    // v1: K=64
    {
        float acc = 0.f;
        int k0 = w*8;
        #pragma unroll
        for (int k = 0; k < 8; ++k) acc += S.u.post.fb[k0+k] * ldv<T>(A.Wv1, (k0+k)*64 + lane);
        S.u.post.mpart[w][lane] = acc;
    }
    __syncthreads();
    float vscale = 0.f;
    if (tid < 64){
        float acc = ldv<T>(A.bv1, tid);
        #pragma unroll
        for (int q = 0; q < 8; ++q) acc += S.u.post.mpart[q][tid];
        float term = siluf(acc) * ldv<T>(A.Wv2, tid);
        #pragma unroll
        for (int off = 1; off < 64; off <<= 1) term += __shfl_xor(term, off);
        vscale = 2.f / (1.f + __expf(-term));
    }
    if (w < 4){
        int c = w*64 + lane;
        float wv = ldv<T>(A.Wvm, c);
        float d0 = S.u.post.red[c*3+0]*sc*wv;
        float d1 = S.u.post.red[c*3+1]*sc*wv;
        float d2 = S.u.post.red[c*3+2]*sc*wv;
        #pragma unroll
        for (int off = 1; off < 64; off <<= 1){
            d0 += __shfl_xor(d0, off); d1 += __shfl_xor(d1, off); d2 += __shfl_xor(d2, off);
        }
        if (lane == 0){ S.u.post.tmp[w][0] = d0; S.u.post.tmp[w][1] = d1; S.u.post.tmp[w][2] = d2; }
    }
    __syncthreads();
    if (tid < 3){
        float dv = S.u.post.tmp[0][tid] + S.u.post.tmp[1][tid] + S.u.post.tmp[2][tid] + S.u.post.tmp[3][tid];
        float vn = dv + vscale * ldv<T>(A.v, bi*3 + tid);
        float xn = ldv<T>(A.x, bi*3 + tid) + vn;
        stv<T>(out, 32768 + bi*3 + tid, xn);  // x_new
        stv<T>(out, 34304 + bi*3 + tid, vn);  // v_new
    }
}

__global__ void __launch_bounds__(512, 4) k_sake(Args A,
                                                 const short* __restrict__ U1w,
                                                 const float* __restrict__ Ajw,
                                                 const short* __restrict__ wxt,
                                                 void* __restrict__ out)
{
    __shared__ Smem S;
    if (detect_f32(A.means)) sake_body<float>(A, U1w, Ajw, wxt, out, S);
    else                     sake_body<bf16 >(A, U1w, Ajw, wxt, out, S);
}

extern "C" void kernel_launch(void* const* d_in, const int* in_sizes, int n_in,
                              void* d_out, int out_size, void* d_ws, size_t ws_size,
                              hipStream_t stream)
{
    Args A;
    A.h     = d_in[0];  A.x     = d_in[1];  A.v     = d_in[2];
    A.Win   = d_in[3];  A.bin   = d_in[4];  A.means = d_in[5];  A.betas = d_in[6];
    A.Wo1   = d_in[7];  A.bo1   = d_in[8];  A.Wo2   = d_in[9];  A.bo2   = d_in[10];
    A.Wsem  = d_in[11]; A.bsem  = d_in[12]; A.Wx    = d_in[13];
    A.Wp1   = d_in[14]; A.bp1   = d_in[15]; A.Wp2   = d_in[16]; A.bp2   = d_in[17];
    A.Wn1   = d_in[18]; A.bn1   = d_in[19]; A.Wn2   = d_in[20]; A.bn2   = d_in[21];
    A.Wv1   = d_in[22]; A.bv1   = d_in[23]; A.Wv2   = d_in[24]; A.Wvm   = d_in[25];

    // ws layout: U1 bf16 512x64 (64KB) | Aj f32 512x64 (128KB) | WxH bf16 4x256x64 (128KB)
    short* U1b  = (short*)d_ws;
    float* Aj   = (float*)((char*)d_ws + 65536);
    short* WxT  = (short*)((char*)d_ws + 65536 + 131072);

    k_nodepre<<<NNODE, 256, 0, stream>>>(A, U1b, Aj, WxT);
    k_sake<<<NNODE, 512, 0, stream>>>(A, U1b, Aj, WxT, d_out);
}